// Round 3
// baseline (858.788 us; speedup 1.0000x reference)
//
#include <hip/hip_runtime.h>

namespace {

constexpr int Dn   = 128;   // model dim
constexpr int DIN  = 512;   // input / output dim
constexpr int Hn   = 8;     // heads
constexpr int Mn   = 128;   // memory slots
constexpr int DFF  = 512;   // ff dim
constexpr int Gn   = 4;     // batches per block == waves per block
constexpr float ATT_SCALE = 0.25f;
constexpr float INV_SQRT2 = 0.70710678118654752440f;
constexpr float DEFER_THR = 4.0f;   // defer-max rescale threshold (p <= e^4)

// dot of a 128-float global row with a 128-float LDS vector
__device__ __forceinline__ float dot128(const float* __restrict__ wrow,
                                        const float* __restrict__ v)
{
    const float4* w4 = (const float4*)wrow;
    const float4* v4 = (const float4*)v;
    float acc = 0.f;
#pragma unroll
    for (int j = 0; j < 32; ++j) {
        float4 a = w4[j], b = v4[j];
        acc += a.x*b.x + a.y*b.y + a.z*b.z + a.w*b.w;
    }
    return acc;
}

// LayerNorm: TPR threads per row, row picked by caller. In-place safe.
template <int NCOL, int TPR>
__device__ __forceinline__ void ln_row(const float* __restrict__ src,
                                       float* __restrict__ dst,
                                       const float* __restrict__ gw,
                                       const float* __restrict__ gb,
                                       const float* __restrict__ resid,
                                       int sub)
{
    constexpr int E = NCOL / TPR;
    float v0[E]; float sm = 0.f;
#pragma unroll
    for (int i = 0; i < E; ++i) { v0[i] = src[sub*E + i]; sm += v0[i]; }
#pragma unroll
    for (int m = TPR/2; m >= 1; m >>= 1) sm += __shfl_xor(sm, m, TPR);
    float mean = sm * (1.f / (float)NCOL);
    float vs = 0.f;
#pragma unroll
    for (int i = 0; i < E; ++i) { float d0 = v0[i] - mean; vs += d0*d0; }
#pragma unroll
    for (int m = TPR/2; m >= 1; m >>= 1) vs += __shfl_xor(vs, m, TPR);
    float rstd = rsqrtf(vs * (1.f / (float)NCOL) + 1e-5f);
#pragma unroll
    for (int i = 0; i < E; ++i) {
        int d = sub*E + i;
        float r = (v0[i] - mean) * rstd * gw[d] + gb[d];
        dst[d] = resid ? (r + resid[d]) : r;
    }
}

__global__ __launch_bounds__(256, 4)
void fused_block(const float* __restrict__ x,
                 const float* __restrict__ W_in,
                 const float* __restrict__ b_in,
                 const float* __restrict__ pos,
                 const float* __restrict__ mask,
                 const float* __restrict__ mem,
                 const float* __restrict__ ln1_w, const float* __restrict__ ln1_b,
                 const float* __restrict__ W_qkv, const float* __restrict__ b_qkv,
                 const float* __restrict__ W_out, const float* __restrict__ b_out,
                 const float* __restrict__ ln2_w, const float* __restrict__ ln2_b,
                 const float* __restrict__ ln3_w, const float* __restrict__ ln3_b,
                 const float* __restrict__ W_ff1, const float* __restrict__ b_ff1,
                 const float* __restrict__ ln4_w, const float* __restrict__ ln4_b,
                 const float* __restrict__ W_ff2, const float* __restrict__ b_ff2,
                 const float* __restrict__ ln5_w, const float* __restrict__ ln5_b,
                 const float* __restrict__ W_head, const float* __restrict__ b_head,
                 float* __restrict__ out)
{
    const int t    = threadIdx.x;
    const int b0   = blockIdx.x * Gn;
    const int lane = t & 63;
    const int wv   = t >> 6;           // wave id == batch slot

    // s_xAq: [Gn][DIN] x-rows (P0/P1)  ->  [Gn][Hn][Dn] Aqw' (P4..P5)  ->  ctxn (P5 end..)
    __shared__ __align__(16) float s_xAq[Gn][Hn][Dn];
    __shared__ __align__(16) float s_qin[Gn][Dn];
    __shared__ __align__(16) float s_lnq[Gn][Dn];
    __shared__ __align__(16) float s_q  [Gn][Dn];    // q, later tmp
    __shared__ __align__(16) float s_mask[Gn][Mn];
    __shared__ float s_s2c[Gn][Hn];
    __shared__ float s_s0 [Gn][Hn];
    __shared__ float s_s1 [Gn][Hn];
    __shared__ __align__(16) float s_hh [Gn][Dn];
    __shared__ __align__(16) float s_f1 [Gn][DFF];
    __shared__ __align__(16) float s_qo [Gn][Dn];

    float* xrow = &s_xAq[0][0][0];     // [Gn][DIN] view

    //--- P0: stage x rows + mask -----------------------------------------
    {
        const float4* src = (const float4*)(x + (size_t)b0 * DIN);
        float4* dst = (float4*)xrow;
        dst[t]       = src[t];
        dst[t + 256] = src[t + 256];
        for (int idx = t; idx < Gn*Mn; idx += 256) {
            int g = idx >> 7, j = idx & 127;
            s_mask[g][j] = mask[(size_t)(b0+g)*Mn + j];
        }
    }
    __syncthreads();

    //--- P1: q_in = x @ W_in^T + b_in + pos -------------------------------
    for (int idx = t; idx < Gn*Dn; idx += 256) {
        int g = idx >> 7, d = idx & 127;
        const float4* w4 = (const float4*)(W_in + (size_t)d * DIN);
        const float4* x4 = (const float4*)(xrow + g*DIN);
        float acc = 0.f;
#pragma unroll 8
        for (int j = 0; j < DIN/4; ++j) {
            float4 a = w4[j], b = x4[j];
            acc += a.x*b.x + a.y*b.y + a.z*b.z + a.w*b.w;
        }
        s_qin[g][d] = acc + b_in[d] + pos[(size_t)(b0+g)*Dn + d];
    }
    __syncthreads();

    //--- P2: lnq = LN(q_in, ln1) ------------------------------------------
    ln_row<Dn, 64>(&s_qin[wv][0], &s_lnq[wv][0], ln1_w, ln1_b, nullptr, lane);
    __syncthreads();

    //--- P3: q = q_in @ Wq^T + bq -----------------------------------------
    for (int idx = t; idx < Gn*Dn; idx += 256) {
        int g = idx >> 7, d = idx & 127;
        s_q[g][d] = dot128(W_qkv + (size_t)d*Dn, &s_qin[g][0]) + b_qkv[d];
    }
    __syncthreads();

    //--- P4: Aqw = (SCALE q_h @ Wk_h) * ln1_w  + per-head scalars ---------
    {
        const int gh = t >> 3, js = t & 7;
        const int g = gh >> 3, h = gh & 7;
        float aqv[16];
#pragma unroll
        for (int jj = 0; jj < 16; ++jj) aqv[jj] = 0.f;
        float ch = 0.f;
#pragma unroll
        for (int d0 = 0; d0 < 16; ++d0) {
            float qv = s_q[g][h*16 + d0];
            const float4* wr4 = (const float4*)(W_qkv + (size_t)(Dn + h*16 + d0)*Dn + js*16);
            float4 w0 = wr4[0], w1 = wr4[1], w2 = wr4[2], w3 = wr4[3];
            aqv[0]  = fmaf(qv, w0.x, aqv[0]);  aqv[1]  = fmaf(qv, w0.y, aqv[1]);
            aqv[2]  = fmaf(qv, w0.z, aqv[2]);  aqv[3]  = fmaf(qv, w0.w, aqv[3]);
            aqv[4]  = fmaf(qv, w1.x, aqv[4]);  aqv[5]  = fmaf(qv, w1.y, aqv[5]);
            aqv[6]  = fmaf(qv, w1.z, aqv[6]);  aqv[7]  = fmaf(qv, w1.w, aqv[7]);
            aqv[8]  = fmaf(qv, w2.x, aqv[8]);  aqv[9]  = fmaf(qv, w2.y, aqv[9]);
            aqv[10] = fmaf(qv, w2.z, aqv[10]); aqv[11] = fmaf(qv, w2.w, aqv[11]);
            aqv[12] = fmaf(qv, w3.x, aqv[12]); aqv[13] = fmaf(qv, w3.y, aqv[13]);
            aqv[14] = fmaf(qv, w3.z, aqv[14]); aqv[15] = fmaf(qv, w3.w, aqv[15]);
            ch = fmaf(qv, b_qkv[Dn + h*16 + d0], ch);
        }
        ch *= ATT_SCALE;
        float s1p = 0.f, s2p = 0.f, s0p = 0.f;
#pragma unroll
        for (int jj = 0; jj < 16; ++jj) {
            int j = js*16 + jj;
            float aq  = ATT_SCALE * aqv[jj];
            float aqw = aq * ln1_w[j];
            s_xAq[g][h][j] = aqw;
            s1p += aqw;
            s2p = fmaf(aq, ln1_b[j], s2p);
            s0p = fmaf(aq, s_lnq[g][j], s0p);
        }
#pragma unroll
        for (int m = 4; m >= 1; m >>= 1) {
            s1p += __shfl_xor(s1p, m, 8);
            s2p += __shfl_xor(s2p, m, 8);
            s0p += __shfl_xor(s0p, m, 8);
        }
        if (js == 0) {
            s_s1 [g][h] = s1p;
            s_s2c[g][h] = s2p + ch;
            s_s0 [g][h] = s0p + ch;
        }
    }
    __syncthreads();
    // P4b: Aqw' = Aqw - s1/128   (folds the -rstd*mean*s1 score term)
    for (int idx = t; idx < Gn*Hn*Dn; idx += 256) {
        int g = idx >> 10, h = (idx >> 7) & 7, j = idx & 127;
        s_xAq[g][h][j] -= s_s1[g][h] * (1.f/128.f);
    }
    __syncthreads();

    //--- P5: wave-local streamed attention (zero barriers inside) ---------
    {
        const int g  = wv;
        const int h2 = lane >> 5;       // which of the 2 rows this iter
        const int c  = lane & 31;       // col group: cols 4c..4c+3

        float aqw[Hn][4];
#pragma unroll
        for (int h = 0; h < Hn; ++h)
            *(float4*)&aqw[h][0] = *(const float4*)&s_xAq[g][h][4*c];

        float m_h[Hn], den[Hn], ctx[Hn][4];
#pragma unroll
        for (int h = 0; h < Hn; ++h) {
            m_h[h] = s_s0[g][h];        // init with kv row 0 (lnq)
            // row-0's unnormalized mass (==1 at m=s0) must live in EXACTLY ONE
            // half-wave state; round-2 bug was den=1 in both halves -> p0
            // double-counted in the denominator after the combine.
            den[h] = (h2 == 0) ? 1.f : 0.f;
            ctx[h][0] = ctx[h][1] = ctx[h][2] = ctx[h][3] = 0.f;
        }
        const float* s2cg = &s_s2c[g][0];

        const float* pbase = mem + (size_t)(b0+g)*Mn*Dn + (size_t)h2*Dn + (size_t)c*4;

        auto STEP = [&](float4 v, int r) {
            float sum = v.x + v.y + v.z + v.w;
            float ssq = v.x*v.x;
            ssq = fmaf(v.y, v.y, ssq); ssq = fmaf(v.z, v.z, ssq); ssq = fmaf(v.w, v.w, ssq);
            float d[Hn];
#pragma unroll
            for (int h = 0; h < Hn; ++h) {
                float a = aqw[h][0]*v.x;
                a = fmaf(aqw[h][1], v.y, a);
                a = fmaf(aqw[h][2], v.z, a);
                a = fmaf(aqw[h][3], v.w, a);
                d[h] = a;
            }
#pragma unroll
            for (int mm = 1; mm < 32; mm <<= 1) {
                sum += __shfl_xor(sum, mm, 32);
                ssq += __shfl_xor(ssq, mm, 32);
#pragma unroll
                for (int h = 0; h < Hn; ++h) d[h] += __shfl_xor(d[h], mm, 32);
            }
            float mean = sum * (1.f/128.f);
            float var  = fmaf(-mean, mean, ssq * (1.f/128.f));
            float rstd = rsqrtf(var + 1e-5f);
            float msk  = s_mask[g][r];
            float sc[Hn];
#pragma unroll
            for (int h = 0; h < Hn; ++h) sc[h] = fmaf(rstd, d[h], s2cg[h]) + msk;

            float grow = sc[0] - m_h[0];
#pragma unroll
            for (int h = 1; h < Hn; ++h) grow = fmaxf(grow, sc[h] - m_h[h]);
            if (grow > DEFER_THR) {     // rare rescale (defer-max)
#pragma unroll
                for (int h = 0; h < Hn; ++h) {
                    float nm = fmaxf(m_h[h], sc[h]);
                    float f  = __expf(m_h[h] - nm);
                    den[h] *= f;
                    ctx[h][0] *= f; ctx[h][1] *= f; ctx[h][2] *= f; ctx[h][3] *= f;
                    m_h[h] = nm;
                }
            }
#pragma unroll
            for (int h = 0; h < Hn; ++h) {
                float p = __expf(sc[h] - m_h[h]);
                den[h] += p;
                float qw = p * rstd;    // fold rstd into ctx weight (raw rows)
                ctx[h][0] = fmaf(qw, v.x, ctx[h][0]);
                ctx[h][1] = fmaf(qw, v.y, ctx[h][1]);
                ctx[h][2] = fmaf(qw, v.z, ctx[h][2]);
                ctx[h][3] = fmaf(qw, v.w, ctx[h][3]);
            }
        };

        float4 f0 = *(const float4*)(pbase +   0);
        float4 f1 = *(const float4*)(pbase + 256);
        float4 f2 = *(const float4*)(pbase + 512);
        float4 f3 = *(const float4*)(pbase + 768);
        for (int i = 0; i < 64; i += 4) {
            { float4 v = f0; if (i+4 < 64) f0 = *(const float4*)(pbase + (size_t)(i+4)*256); STEP(v, 2*i     + h2); }
            { float4 v = f1; if (i+5 < 64) f1 = *(const float4*)(pbase + (size_t)(i+5)*256); STEP(v, 2*(i+1) + h2); }
            { float4 v = f2; if (i+6 < 64) f2 = *(const float4*)(pbase + (size_t)(i+6)*256); STEP(v, 2*(i+2) + h2); }
            { float4 v = f3; if (i+7 < 64) f3 = *(const float4*)(pbase + (size_t)(i+7)*256); STEP(v, 2*(i+3) + h2); }
        }

        // combine the two half-wave online states
#pragma unroll
        for (int h = 0; h < Hn; ++h) {
            float mo = __shfl_xor(m_h[h], 32);
            float M  = fmaxf(m_h[h], mo);
            float f  = __expf(m_h[h] - M);
            den[h] *= f;
            ctx[h][0] *= f; ctx[h][1] *= f; ctx[h][2] *= f; ctx[h][3] *= f;
            m_h[h] = M;
            den[h] += __shfl_xor(den[h], 32);
            ctx[h][0] += __shfl_xor(ctx[h][0], 32);
            ctx[h][1] += __shfl_xor(ctx[h][1], 32);
            ctx[h][2] += __shfl_xor(ctx[h][2], 32);
            ctx[h][3] += __shfl_xor(ctx[h][3], 32);
        }
        // cS_h = (sum_j ctxraw[h][j]) / 128  (== sum_l p*rstd*mean_l)
        float cS[Hn];
#pragma unroll
        for (int h = 0; h < Hn; ++h) {
            float s4 = ctx[h][0] + ctx[h][1] + ctx[h][2] + ctx[h][3];
#pragma unroll
            for (int mm = 1; mm < 32; mm <<= 1) s4 += __shfl_xor(s4, mm, 32);
            cS[h] = s4 * (1.f/128.f);
        }
        // finish: ctx_ln = (p0*lnq + w*(ctxraw - cS) + b*sP) / den  -> ctxn (over Aqw region)
#pragma unroll
        for (int h = 0; h < Hn; ++h) {
            float p0  = __expf(s_s0[g][h] - m_h[h]);
            float sP  = den[h] - p0;
            float inv = 1.f / den[h];
            if (lane < 32) {
#pragma unroll
                for (int c4 = 0; c4 < 4; ++c4) {
                    int j = 4*c + c4;
                    float lnv = p0 * s_lnq[g][j]
                              + ln1_w[j] * (ctx[h][c4] - cS[h])
                              + ln1_b[j] * sP;
                    s_xAq[g][h][j] = lnv * inv;
                }
            }
        }
    }
    __syncthreads();

    //--- P6o: o = Wv @ ctxn + bv ------------------------------------------
    for (int idx = t; idx < Gn*Dn; idx += 256) {
        int g = idx >> 7, i = idx & 127, h = i >> 4;
        s_qo[g][i] = dot128(W_qkv + (size_t)(2*Dn + i)*Dn, &s_xAq[g][h][0]) + b_qkv[2*Dn + i];
    }
    __syncthreads();

    //--- P6a: t1 = o @ W_out^T + b_out -> s_q ----------------------------
    for (int idx = t; idx < Gn*Dn; idx += 256) {
        int g = idx >> 7, d = idx & 127;
        s_q[g][d] = dot128(W_out + (size_t)d*Dn, &s_qo[g][0]) + b_out[d];
    }
    __syncthreads();

    //--- P6b: h = LN(t1, ln2) + q_in --------------------------------------
    ln_row<Dn, 64>(&s_q[wv][0], &s_hh[wv][0], ln2_w, ln2_b, &s_qin[wv][0], lane);
    __syncthreads();

    //--- P6c: ln3h = LN(h, ln3) -> s_q ------------------------------------
    ln_row<Dn, 64>(&s_hh[wv][0], &s_q[wv][0], ln3_w, ln3_b, nullptr, lane);
    __syncthreads();

    //--- P6d: f1 = gelu(ln3h @ W_ff1^T + b_ff1) ---------------------------
    for (int idx = t; idx < Gn*DFF; idx += 256) {
        int g = idx >> 9, e = idx & 511;
        float val = dot128(W_ff1 + (size_t)e*Dn, &s_q[g][0]) + b_ff1[e];
        s_f1[g][e] = 0.5f * val * (1.f + erff(val * INV_SQRT2));
    }
    __syncthreads();

    //--- P6e: LN(f1, ln4) in place ----------------------------------------
    ln_row<DFF, 64>(&s_f1[wv][0], &s_f1[wv][0], ln4_w, ln4_b, nullptr, lane);
    __syncthreads();

    //--- P6f: f2h = f1 @ W_ff2^T + b_ff2 + h -> s_q -----------------------
    for (int idx = t; idx < Gn*Dn; idx += 256) {
        int g = idx >> 7, d = idx & 127;
        const float4* w4 = (const float4*)(W_ff2 + (size_t)d*DFF);
        const float4* v4 = (const float4*)&s_f1[g][0];
        float acc = 0.f;
#pragma unroll 8
        for (int j = 0; j < DFF/4; ++j) {
            float4 a = w4[j], cc = v4[j];
            acc += a.x*cc.x + a.y*cc.y + a.z*cc.z + a.w*cc.w;
        }
        s_q[g][d] = acc + b_ff2[d] + s_hh[g][d];
    }
    __syncthreads();

    //--- P6g: h2 = LN(s_q, ln5) -> s_qo -----------------------------------
    ln_row<Dn, 64>(&s_q[wv][0], &s_qo[wv][0], ln5_w, ln5_b, nullptr, lane);
    __syncthreads();

    //--- P6h: out = h2 @ W_head^T + b_head --------------------------------
    for (int idx = t; idx < Gn*DIN; idx += 256) {
        int g = idx >> 9, e = idx & 511;
        out[(size_t)(b0+g)*DIN + e] = dot128(W_head + (size_t)e*Dn, &s_qo[g][0]) + b_head[e];
    }
}

} // namespace

extern "C" void kernel_launch(void* const* d_in, const int* in_sizes, int n_in,
                              void* d_out, int out_size, void* d_ws, size_t ws_size,
                              hipStream_t stream)
{
    const float* x      = (const float*)d_in[0];
    const float* W_in   = (const float*)d_in[1];
    const float* b_in   = (const float*)d_in[2];
    const float* pos    = (const float*)d_in[3];
    const float* mask   = (const float*)d_in[4];
    const float* mem    = (const float*)d_in[5];
    const float* ln1_w  = (const float*)d_in[6];
    const float* ln1_b  = (const float*)d_in[7];
    const float* W_qkv  = (const float*)d_in[8];
    const float* b_qkv  = (const float*)d_in[9];
    const float* W_out  = (const float*)d_in[10];
    const float* b_out  = (const float*)d_in[11];
    const float* ln2_w  = (const float*)d_in[12];
    const float* ln2_b  = (const float*)d_in[13];
    const float* ln3_w  = (const float*)d_in[14];
    const float* ln3_b  = (const float*)d_in[15];
    const float* W_ff1  = (const float*)d_in[16];
    const float* b_ff1  = (const float*)d_in[17];
    const float* ln4_w  = (const float*)d_in[18];
    const float* ln4_b  = (const float*)d_in[19];
    const float* W_ff2  = (const float*)d_in[20];
    const float* b_ff2  = (const float*)d_in[21];
    const float* ln5_w  = (const float*)d_in[22];
    const float* ln5_b  = (const float*)d_in[23];
    const float* W_head = (const float*)d_in[24];
    const float* b_head = (const float*)d_in[25];

    const int B = in_sizes[0] / DIN;   // 4096
    fused_block<<<dim3(B / Gn), dim3(256), 0, stream>>>(
        x, W_in, b_in, pos, mask, mem,
        ln1_w, ln1_b, W_qkv, b_qkv, W_out, b_out,
        ln2_w, ln2_b, ln3_w, ln3_b,
        W_ff1, b_ff1, ln4_w, ln4_b, W_ff2, b_ff2,
        ln5_w, ln5_b, W_head, b_head,
        (float*)d_out);
}

// Round 4
// 618.139 us; speedup vs baseline: 1.3893x; 1.3893x over previous
//
#include <hip/hip_runtime.h>

namespace {

constexpr int Dn   = 128;   // model dim
constexpr int DIN  = 512;   // input / output dim
constexpr int Hn   = 8;     // heads
constexpr int Mn   = 128;   // memory slots
constexpr int DFF  = 512;   // ff dim
constexpr int Gn   = 4;     // batches per block == waves per block
constexpr float ATT_SCALE = 0.25f;
constexpr float INV_SQRT2 = 0.70710678118654752440f;

// dot of a 128-float global row with a 128-float LDS vector
__device__ __forceinline__ float dot128(const float* __restrict__ wrow,
                                        const float* __restrict__ v)
{
    const float4* w4 = (const float4*)wrow;
    const float4* v4 = (const float4*)v;
    float acc = 0.f;
#pragma unroll
    for (int j = 0; j < 32; ++j) {
        float4 a = w4[j], b = v4[j];
        acc += a.x*b.x + a.y*b.y + a.z*b.z + a.w*b.w;
    }
    return acc;
}

// LayerNorm: TPR threads per row. In-place safe.
template <int NCOL, int TPR>
__device__ __forceinline__ void ln_row(const float* __restrict__ src,
                                       float* __restrict__ dst,
                                       const float* __restrict__ gw,
                                       const float* __restrict__ gb,
                                       const float* __restrict__ resid,
                                       int sub)
{
    constexpr int E = NCOL / TPR;
    float v0[E]; float sm = 0.f;
#pragma unroll
    for (int i = 0; i < E; ++i) { v0[i] = src[sub*E + i]; sm += v0[i]; }
#pragma unroll
    for (int m = TPR/2; m >= 1; m >>= 1) sm += __shfl_xor(sm, m, TPR);
    float mean = sm * (1.f / (float)NCOL);
    float vs = 0.f;
#pragma unroll
    for (int i = 0; i < E; ++i) { float d0 = v0[i] - mean; vs += d0*d0; }
#pragma unroll
    for (int m = TPR/2; m >= 1; m >>= 1) vs += __shfl_xor(vs, m, TPR);
    float rstd = rsqrtf(vs * (1.f / (float)NCOL) + 1e-5f);
#pragma unroll
    for (int i = 0; i < E; ++i) {
        int d = sub*E + i;
        float r = (v0[i] - mean) * rstd * gw[d] + gb[d];
        dst[d] = resid ? (r + resid[d]) : r;
    }
}

__global__ __launch_bounds__(256, 3)
void fused_block(const float* __restrict__ x,
                 const float* __restrict__ W_in,
                 const float* __restrict__ b_in,
                 const float* __restrict__ pos,
                 const float* __restrict__ mask,
                 const float* __restrict__ mem,
                 const float* __restrict__ ln1_w, const float* __restrict__ ln1_b,
                 const float* __restrict__ W_qkv, const float* __restrict__ b_qkv,
                 const float* __restrict__ W_out, const float* __restrict__ b_out,
                 const float* __restrict__ ln2_w, const float* __restrict__ ln2_b,
                 const float* __restrict__ ln3_w, const float* __restrict__ ln3_b,
                 const float* __restrict__ W_ff1, const float* __restrict__ b_ff1,
                 const float* __restrict__ ln4_w, const float* __restrict__ ln4_b,
                 const float* __restrict__ W_ff2, const float* __restrict__ b_ff2,
                 const float* __restrict__ ln5_w, const float* __restrict__ ln5_b,
                 const float* __restrict__ W_head, const float* __restrict__ b_head,
                 float* __restrict__ out)
{
    const int t    = threadIdx.x;
    const int b0   = blockIdx.x * Gn;
    const int lane = t & 63;
    const int wv   = t >> 6;           // wave id == batch slot

    // s_xAq: [Gn][DIN] x-rows (P0/P1) -> [Gn][Hn][Dn] Aqw' (P4..P5A) -> ctxn (P5D..)
    __shared__ __align__(16) float s_xAq[Gn][Hn][Dn];
    __shared__ __align__(16) float s_qin[Gn][Dn];
    __shared__ __align__(16) float s_lnq[Gn][Dn];
    __shared__ __align__(16) float s_q  [Gn][Dn];    // q, later tmp
    __shared__ __align__(16) float s_mask[Gn][Mn];
    __shared__ float s_s2c[Gn][Hn];
    __shared__ float s_s0 [Gn][Hn];
    __shared__ float s_s1 [Gn][Hn];
    __shared__ __align__(16) float s_hh [Gn][Dn];
    __shared__ __align__(16) float s_qo [Gn][Dn];
    // q-weights during attention; f1 during the MLP tail (disjoint in time:
    // a block-wide __syncthreads separates attention from P6d).
    __shared__ __align__(16) union {
        float q [Gn][Mn][8];    // [row][head] = p*rstd, 16 KB
        float f1[Gn][DFF];      // 8 KB
    } s_u;

    float* xrow = &s_xAq[0][0][0];     // [Gn][DIN] view

    //--- P0: stage x rows + mask -------------------------------------------
    {
        const float4* src = (const float4*)(x + (size_t)b0 * DIN);
        float4* dst = (float4*)xrow;
        dst[t]       = src[t];
        dst[t + 256] = src[t + 256];
        for (int idx = t; idx < Gn*Mn; idx += 256) {
            int g = idx >> 7, j = idx & 127;
            s_mask[g][j] = mask[(size_t)(b0+g)*Mn + j];
        }
    }
    __syncthreads();

    //--- P1: q_in = x @ W_in^T + b_in + pos --------------------------------
    for (int idx = t; idx < Gn*Dn; idx += 256) {
        int g = idx >> 7, d = idx & 127;
        const float4* w4 = (const float4*)(W_in + (size_t)d * DIN);
        const float4* x4 = (const float4*)(xrow + g*DIN);
        float acc = 0.f;
#pragma unroll 8
        for (int j = 0; j < DIN/4; ++j) {
            float4 a = w4[j], b = x4[j];
            acc += a.x*b.x + a.y*b.y + a.z*b.z + a.w*b.w;
        }
        s_qin[g][d] = acc + b_in[d] + pos[(size_t)(b0+g)*Dn + d];
    }
    __syncthreads();

    //--- P2: lnq = LN(q_in, ln1) -------------------------------------------
    ln_row<Dn, 64>(&s_qin[wv][0], &s_lnq[wv][0], ln1_w, ln1_b, nullptr, lane);
    __syncthreads();

    //--- P3: q = q_in @ Wq^T + bq ------------------------------------------
    for (int idx = t; idx < Gn*Dn; idx += 256) {
        int g = idx >> 7, d = idx & 127;
        s_q[g][d] = dot128(W_qkv + (size_t)d*Dn, &s_qin[g][0]) + b_qkv[d];
    }
    __syncthreads();

    //--- P4: Aqw = (SCALE q_h @ Wk_h) * ln1_w + per-head scalars -----------
    {
        const int gh = t >> 3, js = t & 7;
        const int g = gh >> 3, h = gh & 7;
        float aqv[16];
#pragma unroll
        for (int jj = 0; jj < 16; ++jj) aqv[jj] = 0.f;
        float ch = 0.f;
#pragma unroll
        for (int d0 = 0; d0 < 16; ++d0) {
            float qv = s_q[g][h*16 + d0];
            const float4* wr4 = (const float4*)(W_qkv + (size_t)(Dn + h*16 + d0)*Dn + js*16);
            float4 w0 = wr4[0], w1 = wr4[1], w2 = wr4[2], w3 = wr4[3];
            aqv[0]  = fmaf(qv, w0.x, aqv[0]);  aqv[1]  = fmaf(qv, w0.y, aqv[1]);
            aqv[2]  = fmaf(qv, w0.z, aqv[2]);  aqv[3]  = fmaf(qv, w0.w, aqv[3]);
            aqv[4]  = fmaf(qv, w1.x, aqv[4]);  aqv[5]  = fmaf(qv, w1.y, aqv[5]);
            aqv[6]  = fmaf(qv, w1.z, aqv[6]);  aqv[7]  = fmaf(qv, w1.w, aqv[7]);
            aqv[8]  = fmaf(qv, w2.x, aqv[8]);  aqv[9]  = fmaf(qv, w2.y, aqv[9]);
            aqv[10] = fmaf(qv, w2.z, aqv[10]); aqv[11] = fmaf(qv, w2.w, aqv[11]);
            aqv[12] = fmaf(qv, w3.x, aqv[12]); aqv[13] = fmaf(qv, w3.y, aqv[13]);
            aqv[14] = fmaf(qv, w3.z, aqv[14]); aqv[15] = fmaf(qv, w3.w, aqv[15]);
            ch = fmaf(qv, b_qkv[Dn + h*16 + d0], ch);
        }
        ch *= ATT_SCALE;
        float s1p = 0.f, s2p = 0.f, s0p = 0.f;
#pragma unroll
        for (int jj = 0; jj < 16; ++jj) {
            int j = js*16 + jj;
            float aq  = ATT_SCALE * aqv[jj];
            float aqw = aq * ln1_w[j];
            s_xAq[g][h][j] = aqw;
            s1p += aqw;
            s2p = fmaf(aq, ln1_b[j], s2p);
            s0p = fmaf(aq, s_lnq[g][j], s0p);
        }
#pragma unroll
        for (int m = 4; m >= 1; m >>= 1) {
            s1p += __shfl_xor(s1p, m, 8);
            s2p += __shfl_xor(s2p, m, 8);
            s0p += __shfl_xor(s0p, m, 8);
        }
        if (js == 0) {
            s_s1 [g][h] = s1p;
            s_s2c[g][h] = s2p + ch;
            s_s0 [g][h] = s0p + ch;
        }
    }
    __syncthreads();
    // P4b: Aqw' = Aqw - s1/128   (folds the -rstd*mean*s1 score term)
    for (int idx = t; idx < Gn*Hn*Dn; idx += 256) {
        int g = idx >> 10, h = (idx >> 7) & 7, j = idx & 127;
        s_xAq[g][h][j] -= s_s1[g][h] * (1.f/128.f);
    }
    __syncthreads();

    //--- P5: two-pass wave-local attention, one-shot softmax ---------------
    // Pass A: row-per-lane scores (zero shuffles per row).
    // Softmax: one 64-lane butterfly per head per batch.
    // Pass C: col-pair-per-lane ctx accumulation (re-read rows via L3).
    {
        const int g = wv;
        const float* mrow = mem + (size_t)(b0+g) * Mn * Dn;

        // Pass A: lane owns rows `lane` and `lane+64`.
        float d0[Hn], d1[Hn];
        float sum0 = 0.f, ssq0 = 0.f, sum1 = 0.f, ssq1 = 0.f;
#pragma unroll
        for (int h = 0; h < Hn; ++h) { d0[h] = 0.f; d1[h] = 0.f; }
        const float4* r0 = (const float4*)(mrow + (size_t)lane * Dn);
        const float4* r1 = (const float4*)(mrow + (size_t)(lane+64) * Dn);
#pragma unroll 4
        for (int j = 0; j < 32; ++j) {
            float4 v0 = r0[j], v1 = r1[j];
            sum0 += v0.x+v0.y+v0.z+v0.w;
            ssq0 = fmaf(v0.x,v0.x,ssq0); ssq0 = fmaf(v0.y,v0.y,ssq0);
            ssq0 = fmaf(v0.z,v0.z,ssq0); ssq0 = fmaf(v0.w,v0.w,ssq0);
            sum1 += v1.x+v1.y+v1.z+v1.w;
            ssq1 = fmaf(v1.x,v1.x,ssq1); ssq1 = fmaf(v1.y,v1.y,ssq1);
            ssq1 = fmaf(v1.z,v1.z,ssq1); ssq1 = fmaf(v1.w,v1.w,ssq1);
#pragma unroll
            for (int h = 0; h < Hn; ++h) {
                float4 a = ((const float4*)&s_xAq[g][h][0])[j];   // broadcast
                d0[h] = fmaf(a.x,v0.x,d0[h]); d0[h] = fmaf(a.y,v0.y,d0[h]);
                d0[h] = fmaf(a.z,v0.z,d0[h]); d0[h] = fmaf(a.w,v0.w,d0[h]);
                d1[h] = fmaf(a.x,v1.x,d1[h]); d1[h] = fmaf(a.y,v1.y,d1[h]);
                d1[h] = fmaf(a.z,v1.z,d1[h]); d1[h] = fmaf(a.w,v1.w,d1[h]);
            }
        }
        float mean0 = sum0 * (1.f/128.f), mean1 = sum1 * (1.f/128.f);
        float rstd0 = rsqrtf(fmaf(-mean0, mean0, ssq0 * (1.f/128.f)) + 1e-5f);
        float rstd1 = rsqrtf(fmaf(-mean1, mean1, ssq1 * (1.f/128.f)) + 1e-5f);
        float msk0 = s_mask[g][lane], msk1 = s_mask[g][lane+64];

        // One-shot softmax per head (all scores materialized; row 0 = lnq/s0).
        float den[Hn], p0v[Hn], q0[Hn], q1[Hn];
#pragma unroll
        for (int h = 0; h < Hn; ++h) {
            float sc0 = fmaf(rstd0, d0[h], s_s2c[g][h]) + msk0;
            float sc1 = fmaf(rstd1, d1[h], s_s2c[g][h]) + msk1;
            float mx = fmaxf(sc0, sc1);
#pragma unroll
            for (int mm = 1; mm < 64; mm <<= 1) mx = fmaxf(mx, __shfl_xor(mx, mm));
            mx = fmaxf(mx, s_s0[g][h]);
            float e0 = __expf(sc0 - mx), e1 = __expf(sc1 - mx);
            float ds = e0 + e1;
#pragma unroll
            for (int mm = 1; mm < 64; mm <<= 1) ds += __shfl_xor(ds, mm);
            p0v[h] = __expf(s_s0[g][h] - mx);
            den[h] = ds + p0v[h];
            q0[h] = e0 * rstd0;     // fold rstd into ctx weight (raw rows)
            q1[h] = e1 * rstd1;
        }
        // stash q-weights: s_u.q[g][row][head]
        *(float4*)&s_u.q[g][lane   ][0] = make_float4(q0[0],q0[1],q0[2],q0[3]);
        *(float4*)&s_u.q[g][lane   ][4] = make_float4(q0[4],q0[5],q0[6],q0[7]);
        *(float4*)&s_u.q[g][lane+64][0] = make_float4(q1[0],q1[1],q1[2],q1[3]);
        *(float4*)&s_u.q[g][lane+64][4] = make_float4(q1[4],q1[5],q1[6],q1[7]);

        // Pass C: lane owns ctx cols 2*lane, 2*lane+1; rows re-read (L3 hit).
        float ctx0[Hn], ctx1[Hn];
#pragma unroll
        for (int h = 0; h < Hn; ++h) { ctx0[h] = 0.f; ctx1[h] = 0.f; }
        const float* crow = mrow + 2*lane;
#pragma unroll 4
        for (int r = 0; r < Mn; ++r) {
            float2 mv = *(const float2*)(crow + (size_t)r * Dn);
            float4 qa = *(const float4*)&s_u.q[g][r][0];   // broadcast
            float4 qb = *(const float4*)&s_u.q[g][r][4];
            ctx0[0]=fmaf(qa.x,mv.x,ctx0[0]); ctx1[0]=fmaf(qa.x,mv.y,ctx1[0]);
            ctx0[1]=fmaf(qa.y,mv.x,ctx0[1]); ctx1[1]=fmaf(qa.y,mv.y,ctx1[1]);
            ctx0[2]=fmaf(qa.z,mv.x,ctx0[2]); ctx1[2]=fmaf(qa.z,mv.y,ctx1[2]);
            ctx0[3]=fmaf(qa.w,mv.x,ctx0[3]); ctx1[3]=fmaf(qa.w,mv.y,ctx1[3]);
            ctx0[4]=fmaf(qb.x,mv.x,ctx0[4]); ctx1[4]=fmaf(qb.x,mv.y,ctx1[4]);
            ctx0[5]=fmaf(qb.y,mv.x,ctx0[5]); ctx1[5]=fmaf(qb.y,mv.y,ctx1[5]);
            ctx0[6]=fmaf(qb.z,mv.x,ctx0[6]); ctx1[6]=fmaf(qb.z,mv.y,ctx1[6]);
            ctx0[7]=fmaf(qb.w,mv.x,ctx0[7]); ctx1[7]=fmaf(qb.w,mv.y,ctx1[7]);
        }

        // Pass D: finish (verified fold): cS, then ctx_ln into s_xAq[g].
#pragma unroll
        for (int h = 0; h < Hn; ++h) {
            float s2 = ctx0[h] + ctx1[h];
#pragma unroll
            for (int mm = 1; mm < 64; mm <<= 1) s2 += __shfl_xor(s2, mm);
            float cS  = s2 * (1.f/128.f);
            float sP  = den[h] - p0v[h];
            float inv = 1.f / den[h];
            int j0 = 2*lane, j1 = j0 + 1;
            float l0 = p0v[h]*s_lnq[g][j0] + ln1_w[j0]*(ctx0[h]-cS) + ln1_b[j0]*sP;
            float l1 = p0v[h]*s_lnq[g][j1] + ln1_w[j1]*(ctx1[h]-cS) + ln1_b[j1]*sP;
            s_xAq[g][h][j0] = l0 * inv;
            s_xAq[g][h][j1] = l1 * inv;
        }
    }
    __syncthreads();

    //--- P6o: o = Wv @ ctxn + bv -------------------------------------------
    for (int idx = t; idx < Gn*Dn; idx += 256) {
        int g = idx >> 7, i = idx & 127, h = i >> 4;
        s_qo[g][i] = dot128(W_qkv + (size_t)(2*Dn + i)*Dn, &s_xAq[g][h][0]) + b_qkv[2*Dn + i];
    }
    __syncthreads();

    //--- P6a: t1 = o @ W_out^T + b_out -> s_q ------------------------------
    for (int idx = t; idx < Gn*Dn; idx += 256) {
        int g = idx >> 7, d = idx & 127;
        s_q[g][d] = dot128(W_out + (size_t)d*Dn, &s_qo[g][0]) + b_out[d];
    }
    __syncthreads();

    //--- P6b: h = LN(t1, ln2) + q_in ---------------------------------------
    ln_row<Dn, 64>(&s_q[wv][0], &s_hh[wv][0], ln2_w, ln2_b, &s_qin[wv][0], lane);
    __syncthreads();

    //--- P6c: ln3h = LN(h, ln3) -> s_q -------------------------------------
    ln_row<Dn, 64>(&s_hh[wv][0], &s_q[wv][0], ln3_w, ln3_b, nullptr, lane);
    __syncthreads();

    //--- P6d: f1 = gelu(ln3h @ W_ff1^T + b_ff1) ----------------------------
    for (int idx = t; idx < Gn*DFF; idx += 256) {
        int g = idx >> 9, e = idx & 511;
        float val = dot128(W_ff1 + (size_t)e*Dn, &s_q[g][0]) + b_ff1[e];
        s_u.f1[g][e] = 0.5f * val * (1.f + erff(val * INV_SQRT2));
    }
    __syncthreads();

    //--- P6e: LN(f1, ln4) in place -----------------------------------------
    ln_row<DFF, 64>(&s_u.f1[wv][0], &s_u.f1[wv][0], ln4_w, ln4_b, nullptr, lane);
    __syncthreads();

    //--- P6f: f2h = f1 @ W_ff2^T + b_ff2 + h -> s_q ------------------------
    for (int idx = t; idx < Gn*Dn; idx += 256) {
        int g = idx >> 7, d = idx & 127;
        const float4* w4 = (const float4*)(W_ff2 + (size_t)d*DFF);
        const float4* v4 = (const float4*)&s_u.f1[g][0];
        float acc = 0.f;
#pragma unroll 8
        for (int j = 0; j < DFF/4; ++j) {
            float4 a = w4[j], cc = v4[j];
            acc += a.x*cc.x + a.y*cc.y + a.z*cc.z + a.w*cc.w;
        }
        s_q[g][d] = acc + b_ff2[d] + s_hh[g][d];
    }
    __syncthreads();

    //--- P6g: h2 = LN(s_q, ln5) -> s_qo ------------------------------------
    ln_row<Dn, 64>(&s_q[wv][0], &s_qo[wv][0], ln5_w, ln5_b, nullptr, lane);
    __syncthreads();

    //--- P6h: out = h2 @ W_head^T + b_head ---------------------------------
    for (int idx = t; idx < Gn*DIN; idx += 256) {
        int g = idx >> 9, e = idx & 511;
        out[(size_t)(b0+g)*DIN + e] = dot128(W_head + (size_t)e*Dn, &s_qo[g][0]) + b_head[e];
    }
}

} // namespace

extern "C" void kernel_launch(void* const* d_in, const int* in_sizes, int n_in,
                              void* d_out, int out_size, void* d_ws, size_t ws_size,
                              hipStream_t stream)
{
    const float* x      = (const float*)d_in[0];
    const float* W_in   = (const float*)d_in[1];
    const float* b_in   = (const float*)d_in[2];
    const float* pos    = (const float*)d_in[3];
    const float* mask   = (const float*)d_in[4];
    const float* mem    = (const float*)d_in[5];
    const float* ln1_w  = (const float*)d_in[6];
    const float* ln1_b  = (const float*)d_in[7];
    const float* W_qkv  = (const float*)d_in[8];
    const float* b_qkv  = (const float*)d_in[9];
    const float* W_out  = (const float*)d_in[10];
    const float* b_out  = (const float*)d_in[11];
    const float* ln2_w  = (const float*)d_in[12];
    const float* ln2_b  = (const float*)d_in[13];
    const float* ln3_w  = (const float*)d_in[14];
    const float* ln3_b  = (const float*)d_in[15];
    const float* W_ff1  = (const float*)d_in[16];
    const float* b_ff1  = (const float*)d_in[17];
    const float* ln4_w  = (const float*)d_in[18];
    const float* ln4_b  = (const float*)d_in[19];
    const float* W_ff2  = (const float*)d_in[20];
    const float* b_ff2  = (const float*)d_in[21];
    const float* ln5_w  = (const float*)d_in[22];
    const float* ln5_b  = (const float*)d_in[23];
    const float* W_head = (const float*)d_in[24];
    const float* b_head = (const float*)d_in[25];

    const int B = in_sizes[0] / DIN;   // 4096
    fused_block<<<dim3(B / Gn), dim3(256), 0, stream>>>(
        x, W_in, b_in, pos, mask, mem,
        ln1_w, ln1_b, W_qkv, b_qkv, W_out, b_out,
        ln2_w, ln2_b, ln3_w, ln3_b,
        W_ff1, b_ff1, ln4_w, ln4_b, W_ff2, b_ff2,
        ln5_w, ln5_b, W_head, b_head,
        (float*)d_out);
}

// Round 5
// 283.693 us; speedup vs baseline: 3.0272x; 2.1789x over previous
//
#include <hip/hip_runtime.h>

namespace {

constexpr int Dn   = 128;   // model dim
constexpr int DIN  = 512;   // input / output dim
constexpr int Hn   = 8;     // heads
constexpr int Mn   = 128;   // memory slots
constexpr int DFF  = 512;   // ff dim
constexpr int Gn   = 4;     // batches per block (attention processed sequentially)
constexpr float ATT_SCALE = 0.25f;
constexpr float INV_SQRT2 = 0.70710678118654752440f;

// dot of a 128-float global row with a 128-float LDS vector
__device__ __forceinline__ float dot128(const float* __restrict__ wrow,
                                        const float* __restrict__ v)
{
    const float4* w4 = (const float4*)wrow;
    const float4* v4 = (const float4*)v;
    float acc = 0.f;
#pragma unroll
    for (int j = 0; j < 32; ++j) {
        float4 a = w4[j], b = v4[j];
        acc += a.x*b.x + a.y*b.y + a.z*b.z + a.w*b.w;
    }
    return acc;
}

// LayerNorm: TPR threads per row. In-place safe.
template <int NCOL, int TPR>
__device__ __forceinline__ void ln_row(const float* __restrict__ src,
                                       float* __restrict__ dst,
                                       const float* __restrict__ gw,
                                       const float* __restrict__ gb,
                                       const float* __restrict__ resid,
                                       int sub)
{
    constexpr int E = NCOL / TPR;
    float v0[E]; float sm = 0.f;
#pragma unroll
    for (int i = 0; i < E; ++i) { v0[i] = src[sub*E + i]; sm += v0[i]; }
#pragma unroll
    for (int m = TPR/2; m >= 1; m >>= 1) sm += __shfl_xor(sm, m, TPR);
    float mean = sm * (1.f / (float)NCOL);
    float vs = 0.f;
#pragma unroll
    for (int i = 0; i < E; ++i) { float d0 = v0[i] - mean; vs += d0*d0; }
#pragma unroll
    for (int m = TPR/2; m >= 1; m >>= 1) vs += __shfl_xor(vs, m, TPR);
    float rstd = rsqrtf(vs * (1.f / (float)NCOL) + 1e-5f);
#pragma unroll
    for (int i = 0; i < E; ++i) {
        int d = sub*E + i;
        float r = (v0[i] - mean) * rstd * gw[d] + gb[d];
        dst[d] = resid ? (r + resid[d]) : r;
    }
}

__global__ __launch_bounds__(256, 2)
void fused_block(const float* __restrict__ x,
                 const float* __restrict__ W_in,
                 const float* __restrict__ b_in,
                 const float* __restrict__ pos,
                 const float* __restrict__ mask,
                 const float* __restrict__ mem,
                 const float* __restrict__ ln1_w, const float* __restrict__ ln1_b,
                 const float* __restrict__ W_qkv, const float* __restrict__ b_qkv,
                 const float* __restrict__ W_out, const float* __restrict__ b_out,
                 const float* __restrict__ ln2_w, const float* __restrict__ ln2_b,
                 const float* __restrict__ ln3_w, const float* __restrict__ ln3_b,
                 const float* __restrict__ W_ff1, const float* __restrict__ b_ff1,
                 const float* __restrict__ ln4_w, const float* __restrict__ ln4_b,
                 const float* __restrict__ W_ff2, const float* __restrict__ b_ff2,
                 const float* __restrict__ ln5_w, const float* __restrict__ ln5_b,
                 const float* __restrict__ W_head, const float* __restrict__ b_head,
                 float* __restrict__ out)
{
    const int t    = threadIdx.x;
    const int b0   = blockIdx.x * Gn;
    const int lane = t & 63;
    const int wv   = t >> 6;

    __shared__ __align__(16) float s_mem[Mn * Dn];          // x[4][512] -> mem tile -> f1[4][512]
    __shared__ __align__(16) float s_A [Hn][Dn];            // Aq' -> ctxn (current batch)
    __shared__ __align__(16) float s_sc[Hn][Mn];            // scores -> qw; later tmp[4][128]
    __shared__ __align__(16) float s_rstd[Mn];
    __shared__ __align__(16) float s_lnq[Dn];
    __shared__ __align__(16) float s_q  [Dn];
    __shared__ __align__(16) float s_qin[Gn][Dn];
    __shared__ __align__(16) float s_hh [Gn][Dn];
    __shared__ __align__(16) float s_qo [Gn][Dn];           // o; later h2
    __shared__ float s_s1[Hn], s_s2c[Hn], s_s0[Hn], s_den[Hn], s_p0[Hn];

    float4* mem4 = (float4*)s_mem;
    float (*s_tmp)[Dn] = (float(*)[Dn])&s_sc[0][0];

    //--- P0: stage x rows (flat [4][512]) ----------------------------------
    {
        const float4* src = (const float4*)(x + (size_t)b0 * DIN);
        mem4[t]       = src[t];
        mem4[t + 256] = src[t + 256];
    }
    __syncthreads();

    //--- P1: q_in = x @ W_in^T + b_in + pos  (batched matvec) --------------
    if (t < Dn) {
        const float4* w4 = (const float4*)(W_in + (size_t)t * DIN);
        float acc[Gn] = {0.f, 0.f, 0.f, 0.f};
        for (int j = 0; j < DIN/4; ++j) {
            float4 a = w4[j];
#pragma unroll
            for (int g = 0; g < Gn; ++g) {
                float4 xv = mem4[g*(DIN/4) + j];
                acc[g] = fmaf(a.x, xv.x, acc[g]); acc[g] = fmaf(a.y, xv.y, acc[g]);
                acc[g] = fmaf(a.z, xv.z, acc[g]); acc[g] = fmaf(a.w, xv.w, acc[g]);
            }
        }
#pragma unroll
        for (int g = 0; g < Gn; ++g)
            s_qin[g][t] = acc[g] + b_in[t] + pos[(size_t)(b0+g)*Dn + t];
    }
    __syncthreads();

    //--- Attention: per batch, full mem tile in LDS (XOR-swizzled) ---------
    for (int g = 0; g < Gn; ++g) {
        __syncthreads();   // protect s_mem/s_q/s_lnq/s_A from previous iter

        {
            const float4* src = (const float4*)(mem + (size_t)(b0+g) * Mn * Dn);
#pragma unroll
            for (int i = 0; i < 16; ++i) {
                int fid = t + 256*i;
                int r = fid >> 5, k = fid & 31;
                mem4[r*32 + (k ^ (r & 7))] = src[fid];
            }
        }
        if (t < 64) {
            ln_row<Dn, 64>(&s_qin[g][0], s_lnq, ln1_w, ln1_b, nullptr, t);
        } else if (t >= 128) {
            int dd = t - 128;
            s_q[dd] = dot128(W_qkv + (size_t)dd*Dn, &s_qin[g][0]) + b_qkv[dd];
        }
        __syncthreads();

        // Aq-JIT: Aqw = SCALE*(q_h @ Wk_h)*ln1_w + scalars s1/s2c/s0
        {
            int h = t >> 5, js = t & 31;
            float aq[4] = {0.f, 0.f, 0.f, 0.f};
            float ch = 0.f;
#pragma unroll
            for (int d0 = 0; d0 < 16; ++d0) {
                float qv = s_q[h*16 + d0];
                float4 w = ((const float4*)(W_qkv + (size_t)(Dn + h*16 + d0)*Dn))[js];
                aq[0] = fmaf(qv, w.x, aq[0]); aq[1] = fmaf(qv, w.y, aq[1]);
                aq[2] = fmaf(qv, w.z, aq[2]); aq[3] = fmaf(qv, w.w, aq[3]);
                ch = fmaf(qv, b_qkv[Dn + h*16 + d0], ch);
            }
            float s1p = 0.f, s2p = 0.f, s0p = 0.f;
            float aqw[4];
#pragma unroll
            for (int c = 0; c < 4; ++c) {
                int j = 4*js + c;
                float a = ATT_SCALE * aq[c];
                aqw[c] = a * ln1_w[j];
                s1p += aqw[c];
                s2p = fmaf(a, ln1_b[j], s2p);
                s0p = fmaf(a, s_lnq[j], s0p);
            }
            *(float4*)&s_A[h][4*js] = make_float4(aqw[0], aqw[1], aqw[2], aqw[3]);
            ch *= ATT_SCALE;
#pragma unroll
            for (int m = 16; m >= 1; m >>= 1) {
                s1p += __shfl_xor(s1p, m, 32);
                s2p += __shfl_xor(s2p, m, 32);
                s0p += __shfl_xor(s0p, m, 32);
            }
            if (js == 0) { s_s1[h] = s1p; s_s2c[h] = s2p + ch; s_s0[h] = s0p + ch; }
        }
        __syncthreads();
        {   // Aqw' = Aqw - s1/128
            int h = t >> 5;
            float sub = s_s1[h] * (1.f/128.f);
            float4* p = (float4*)&s_A[0][0] + t;
            float4 v = *p;
            v.x -= sub; v.y -= sub; v.z -= sub; v.w -= sub;
            *p = v;
        }
        __syncthreads();

        // Pass A: scores, 2 lanes per row from swizzled LDS
        {
            int r = t >> 1, hf = t & 1;
            float d[Hn];
#pragma unroll
            for (int h = 0; h < Hn; ++h) d[h] = 0.f;
            float sum = 0.f, ssq = 0.f;
#pragma unroll
            for (int kk = 0; kk < 16; ++kk) {
                int k = hf*16 + kk;
                float4 v = mem4[r*32 + (k ^ (r & 7))];
                sum += v.x + v.y + v.z + v.w;
                ssq = fmaf(v.x, v.x, ssq); ssq = fmaf(v.y, v.y, ssq);
                ssq = fmaf(v.z, v.z, ssq); ssq = fmaf(v.w, v.w, ssq);
#pragma unroll
                for (int h = 0; h < Hn; ++h) {
                    float4 a = ((const float4*)&s_A[h][0])[k];
                    d[h] = fmaf(a.x, v.x, d[h]); d[h] = fmaf(a.y, v.y, d[h]);
                    d[h] = fmaf(a.z, v.z, d[h]); d[h] = fmaf(a.w, v.w, d[h]);
                }
            }
            sum += __shfl_xor(sum, 1);
            ssq += __shfl_xor(ssq, 1);
#pragma unroll
            for (int h = 0; h < Hn; ++h) d[h] += __shfl_xor(d[h], 1);
            if (hf == 0) {
                float mean = sum * (1.f/128.f);
                float var  = fmaf(-mean, mean, ssq * (1.f/128.f));
                float rstd = rsqrtf(var + 1e-5f);
                float msk  = mask[(size_t)(b0+g)*Mn + r];
                s_rstd[r] = rstd;
#pragma unroll
                for (int h = 0; h < Hn; ++h)
                    s_sc[h][r] = fmaf(rstd, d[h], s_s2c[h]) + msk;
            }
        }
        __syncthreads();

        // One-shot softmax -> qw (in place), den/p0 per head
        {
            int h = t >> 5, s = t & 31;
            float4 sv = ((float4*)&s_sc[h][0])[s];
            float s0 = s_s0[h];
            float mx = fmaxf(fmaxf(sv.x, sv.y), fmaxf(sv.z, sv.w));
#pragma unroll
            for (int m = 16; m >= 1; m >>= 1) mx = fmaxf(mx, __shfl_xor(mx, m, 32));
            mx = fmaxf(mx, s0);
            float e0 = __expf(sv.x - mx), e1 = __expf(sv.y - mx);
            float e2 = __expf(sv.z - mx), e3 = __expf(sv.w - mx);
            float ds = e0 + e1 + e2 + e3;
#pragma unroll
            for (int m = 16; m >= 1; m >>= 1) ds += __shfl_xor(ds, m, 32);
            float p0 = __expf(s0 - mx);
            float4 rs = ((float4*)s_rstd)[s];
            ((float4*)&s_sc[h][0])[s] =
                make_float4(e0*rs.x, e1*rs.y, e2*rs.z, e3*rs.w);
            if (s == 0) { s_den[h] = ds + p0; s_p0[h] = p0; }
        }
        __syncthreads();

        // Pass C: ctx (wave-per-head-pair, col-pair-per-lane) + Pass D
        {
            int w = t >> 6, l = t & 63;
            int h0 = 2*w, h1 = 2*w + 1;
            int slot = l >> 1, half = l & 1;
            float c00 = 0.f, c01 = 0.f, c10 = 0.f, c11 = 0.f;
#pragma unroll 4
            for (int r = 0; r < Mn; ++r) {
                float2 mv = *(const float2*)(s_mem + r*Dn + ((slot ^ (r & 7)) << 2) + half*2);
                float q0 = s_sc[h0][r], q1 = s_sc[h1][r];
                c00 = fmaf(q0, mv.x, c00); c01 = fmaf(q0, mv.y, c01);
                c10 = fmaf(q1, mv.x, c10); c11 = fmaf(q1, mv.y, c11);
            }
            float r0 = c00 + c01, r1 = c10 + c11;
#pragma unroll
            for (int m = 1; m < 64; m <<= 1) {
                r0 += __shfl_xor(r0, m);
                r1 += __shfl_xor(r1, m);
            }
            float cS0 = r0 * (1.f/128.f), cS1 = r1 * (1.f/128.f);
            int j0 = 2*l, j1 = 2*l + 1;
            float den0 = s_den[h0], p00 = s_p0[h0], sP0 = den0 - p00, inv0 = 1.f/den0;
            float den1 = s_den[h1], p01 = s_p0[h1], sP1 = den1 - p01, inv1 = 1.f/den1;
            float lq0 = s_lnq[j0], lq1 = s_lnq[j1];
            float w0 = ln1_w[j0], w1 = ln1_w[j1];
            float bb0 = ln1_b[j0], bb1 = ln1_b[j1];
            *(float2*)&s_A[h0][j0] =
                make_float2((p00*lq0 + w0*(c00 - cS0) + bb0*sP0) * inv0,
                            (p00*lq1 + w1*(c01 - cS0) + bb1*sP0) * inv0);
            *(float2*)&s_A[h1][j0] =
                make_float2((p01*lq0 + w0*(c10 - cS1) + bb0*sP1) * inv1,
                            (p01*lq1 + w1*(c11 - cS1) + bb1*sP1) * inv1);
        }
        __syncthreads();

        // P6o: o = Wv @ ctxn + bv  (per batch)
        if (t < Dn) {
            int h = t >> 4;
            s_qo[g][t] = dot128(W_qkv + (size_t)(2*Dn + t)*Dn, &s_A[h][0])
                       + b_qkv[2*Dn + t];
        }
    }
    __syncthreads();

    //--- P6a: t1 = o @ W_out^T + b_out (batched) ---------------------------
    if (t < Dn) {
        const float4* w4 = (const float4*)(W_out + (size_t)t * Dn);
        float acc[Gn] = {0.f, 0.f, 0.f, 0.f};
#pragma unroll 8
        for (int j = 0; j < 32; ++j) {
            float4 a = w4[j];
#pragma unroll
            for (int g = 0; g < Gn; ++g) {
                float4 v = ((const float4*)&s_qo[g][0])[j];
                acc[g] = fmaf(a.x, v.x, acc[g]); acc[g] = fmaf(a.y, v.y, acc[g]);
                acc[g] = fmaf(a.z, v.z, acc[g]); acc[g] = fmaf(a.w, v.w, acc[g]);
            }
        }
#pragma unroll
        for (int g = 0; g < Gn; ++g) s_tmp[g][t] = acc[g] + b_out[t];
    }
    __syncthreads();

    //--- P6b: h = LN(t1, ln2) + q_in ---------------------------------------
    ln_row<Dn, 64>(&s_tmp[wv][0], &s_hh[wv][0], ln2_w, ln2_b, &s_qin[wv][0], lane);
    __syncthreads();

    //--- P6c: ln3h = LN(h, ln3) -> s_qin -----------------------------------
    ln_row<Dn, 64>(&s_hh[wv][0], &s_qin[wv][0], ln3_w, ln3_b, nullptr, lane);
    __syncthreads();

    //--- P6d: f1 = gelu(ln3h @ W_ff1^T + b_ff1) -> s_mem [4][512] ----------
    {
        int e0 = t, e1 = t + 256;
        const float4* wa = (const float4*)(W_ff1 + (size_t)e0 * Dn);
        const float4* wb = (const float4*)(W_ff1 + (size_t)e1 * Dn);
        float acc0[Gn] = {0.f,0.f,0.f,0.f}, acc1[Gn] = {0.f,0.f,0.f,0.f};
#pragma unroll 4
        for (int j = 0; j < 32; ++j) {
            float4 a = wa[j], b = wb[j];
#pragma unroll
            for (int g = 0; g < Gn; ++g) {
                float4 v = ((const float4*)&s_qin[g][0])[j];
                acc0[g] = fmaf(a.x, v.x, acc0[g]); acc0[g] = fmaf(a.y, v.y, acc0[g]);
                acc0[g] = fmaf(a.z, v.z, acc0[g]); acc0[g] = fmaf(a.w, v.w, acc0[g]);
                acc1[g] = fmaf(b.x, v.x, acc1[g]); acc1[g] = fmaf(b.y, v.y, acc1[g]);
                acc1[g] = fmaf(b.z, v.z, acc1[g]); acc1[g] = fmaf(b.w, v.w, acc1[g]);
            }
        }
#pragma unroll
        for (int g = 0; g < Gn; ++g) {
            float v0 = acc0[g] + b_ff1[e0];
            float v1 = acc1[g] + b_ff1[e1];
            s_mem[g*DFF + e0] = 0.5f * v0 * (1.f + erff(v0 * INV_SQRT2));
            s_mem[g*DFF + e1] = 0.5f * v1 * (1.f + erff(v1 * INV_SQRT2));
        }
    }
    __syncthreads();

    //--- P6e: LN(f1, ln4) in place -----------------------------------------
    ln_row<DFF, 64>(s_mem + wv*DFF, s_mem + wv*DFF, ln4_w, ln4_b, nullptr, lane);
    __syncthreads();

    //--- P6f: f2h = f1 @ W_ff2^T + b_ff2 + h -> s_tmp ----------------------
    if (t < Dn) {
        const float4* w4 = (const float4*)(W_ff2 + (size_t)t * DFF);
        float acc[Gn] = {0.f, 0.f, 0.f, 0.f};
#pragma unroll 4
        for (int j = 0; j < DFF/4; ++j) {
            float4 a = w4[j];
#pragma unroll
            for (int g = 0; g < Gn; ++g) {
                float4 v = ((const float4*)(s_mem + g*DFF))[j];
                acc[g] = fmaf(a.x, v.x, acc[g]); acc[g] = fmaf(a.y, v.y, acc[g]);
                acc[g] = fmaf(a.z, v.z, acc[g]); acc[g] = fmaf(a.w, v.w, acc[g]);
            }
        }
#pragma unroll
        for (int g = 0; g < Gn; ++g)
            s_tmp[g][t] = acc[g] + b_ff2[t] + s_hh[g][t];
    }
    __syncthreads();

    //--- P6g: h2 = LN(s_tmp, ln5) -> s_qo ----------------------------------
    ln_row<Dn, 64>(&s_tmp[wv][0], &s_qo[wv][0], ln5_w, ln5_b, nullptr, lane);
    __syncthreads();

    //--- P6h: out = h2 @ W_head^T + b_head (batched) -----------------------
    {
        int e0 = t, e1 = t + 256;
        const float4* wa = (const float4*)(W_head + (size_t)e0 * Dn);
        const float4* wb = (const float4*)(W_head + (size_t)e1 * Dn);
        float acc0[Gn] = {0.f,0.f,0.f,0.f}, acc1[Gn] = {0.f,0.f,0.f,0.f};
#pragma unroll 4
        for (int j = 0; j < 32; ++j) {
            float4 a = wa[j], b = wb[j];
#pragma unroll
            for (int g = 0; g < Gn; ++g) {
                float4 v = ((const float4*)&s_qo[g][0])[j];
                acc0[g] = fmaf(a.x, v.x, acc0[g]); acc0[g] = fmaf(a.y, v.y, acc0[g]);
                acc0[g] = fmaf(a.z, v.z, acc0[g]); acc0[g] = fmaf(a.w, v.w, acc0[g]);
                acc1[g] = fmaf(b.x, v.x, acc1[g]); acc1[g] = fmaf(b.y, v.y, acc1[g]);
                acc1[g] = fmaf(b.z, v.z, acc1[g]); acc1[g] = fmaf(b.w, v.w, acc1[g]);
            }
        }
#pragma unroll
        for (int g = 0; g < Gn; ++g) {
            out[(size_t)(b0+g)*DIN + e0] = acc0[g] + b_head[e0];
            out[(size_t)(b0+g)*DIN + e1] = acc1[g] + b_head[e1];
        }
    }
}

} // namespace

extern "C" void kernel_launch(void* const* d_in, const int* in_sizes, int n_in,
                              void* d_out, int out_size, void* d_ws, size_t ws_size,
                              hipStream_t stream)
{
    const float* x      = (const float*)d_in[0];
    const float* W_in   = (const float*)d_in[1];
    const float* b_in   = (const float*)d_in[2];
    const float* pos    = (const float*)d_in[3];
    const float* mask   = (const float*)d_in[4];
    const float* mem    = (const float*)d_in[5];
    const float* ln1_w  = (const float*)d_in[6];
    const float* ln1_b  = (const float*)d_in[7];
    const float* W_qkv  = (const float*)d_in[8];
    const float* b_qkv  = (const float*)d_in[9];
    const float* W_out  = (const float*)d_in[10];
    const float* b_out  = (const float*)d_in[11];
    const float* ln2_w  = (const float*)d_in[12];
    const float* ln2_b  = (const float*)d_in[13];
    const float* ln3_w  = (const float*)d_in[14];
    const float* ln3_b  = (const float*)d_in[15];
    const float* W_ff1  = (const float*)d_in[16];
    const float* b_ff1  = (const float*)d_in[17];
    const float* ln4_w  = (const float*)d_in[18];
    const float* ln4_b  = (const float*)d_in[19];
    const float* W_ff2  = (const float*)d_in[20];
    const float* b_ff2  = (const float*)d_in[21];
    const float* ln5_w  = (const float*)d_in[22];
    const float* ln5_b  = (const float*)d_in[23];
    const float* W_head = (const float*)d_in[24];
    const float* b_head = (const float*)d_in[25];

    const int B = in_sizes[0] / DIN;   // 4096
    fused_block<<<dim3(B / Gn), dim3(256), 0, stream>>>(
        x, W_in, b_in, pos, mask, mem,
        ln1_w, ln1_b, W_qkv, b_qkv, W_out, b_out,
        ln2_w, ln2_b, ln3_w, ln3_b,
        W_ff1, b_ff1, ln4_w, ln4_b, W_ff2, b_ff2,
        ln5_w, ln5_b, W_head, b_head,
        (float*)d_out);
}